// Round 13
// baseline (475.207 us; speedup 1.0000x reference)
//
#include <hip/hip_runtime.h>

typedef __attribute__((ext_vector_type(8))) short s8v;   // 8 x bf16 (4 VGPRs)
typedef __attribute__((ext_vector_type(4))) float f4v;   // mfma accumulator

#define LOG2E 1.44269504088896340736f
#define C1 (0.125f * LOG2E)
#define SLEN 2048

union U4 { uint4 u; s8v v; };
static __device__ __forceinline__ s8v asv(uint4 u) { U4 c; c.u = u; return c.v; }

// fp32 -> bf16 round-half-up pack: low short = bf16(a), high short = bf16(b)
static __device__ __forceinline__ unsigned int pk2(float a, float b) {
    unsigned int ua = __float_as_uint(a) + 0x8000u;
    unsigned int ub = __float_as_uint(b) + 0x8000u;
    return __builtin_amdgcn_perm(ub, ua, 0x07060302u);
}

// single-instr RNE pack (hot loop only): low = bf16(a), high = bf16(b)
static __device__ __forceinline__ unsigned int cvtpk(float a, float b) {
    unsigned int r;
    asm("v_cvt_pk_bf16_f32 %0, %1, %2" : "=v"(r) : "v"(a), "v"(b));
    return r;
}

// raw HW exp2: 1 TRANS instr (libm exp2f expands to ~7; FTZ is right for softmax)
static __device__ __forceinline__ float fexp2(float x) {
    float r;
    asm("v_exp_f32 %0, %1" : "=v"(r) : "v"(x));
    return r;
}

// ============ prep: one-shot bf16 conversion into PER-WAVE FRAGMENT order ============
// (unchanged from round 11)
__global__ __launch_bounds__(256)
void prep_kernel(const float* __restrict__ K, const float* __restrict__ V,
                 const float* __restrict__ W,
                 unsigned short* __restrict__ KF, unsigned short* __restrict__ VF,
                 unsigned short* __restrict__ Wb) {
    __shared__ __attribute__((aligned(16))) unsigned short T[64 * 72];    // V tile
    __shared__ __attribute__((aligned(16))) unsigned short T2[64 * 80];   // K tile
    const int b = blockIdx.x, tid = threadIdx.x;
    if (b < 1024) {                       // K + V tile job: b = pair*32 + kvt
        const int pair = b >> 5, kvt = b & 31, kvt2 = kvt >> 1, parity = kvt & 1;
        const float* Kf = K + (size_t)b * 4096;
        const float* Vf = V + (size_t)b * 4096;
        {   // stage V -> T[kv][72] and K -> T2[kv][80], both coalesced
            int r = tid >> 2, c0 = (tid & 3) * 16;
            const float* sv = Vf + r * 64 + c0;
            float4 a = *(const float4*)sv,       bb = *(const float4*)(sv + 4);
            float4 c = *(const float4*)(sv + 8), d  = *(const float4*)(sv + 12);
            *(uint4*)&T[r * 72 + c0]     = make_uint4(pk2(a.x,a.y), pk2(a.z,a.w), pk2(bb.x,bb.y), pk2(bb.z,bb.w));
            *(uint4*)&T[r * 72 + c0 + 8] = make_uint4(pk2(c.x,c.y), pk2(c.z,c.w), pk2(d.x,d.y),   pk2(d.z,d.w));
            const float* sk = Kf + r * 64 + c0;
            float4 e = *(const float4*)sk,       ff = *(const float4*)(sk + 4);
            float4 g = *(const float4*)(sk + 8), h  = *(const float4*)(sk + 12);
            *(uint4*)&T2[r * 80 + c0]     = make_uint4(pk2(e.x,e.y), pk2(e.z,e.w), pk2(ff.x,ff.y), pk2(ff.z,ff.w));
            *(uint4*)&T2[r * 80 + c0 + 8] = make_uint4(pk2(g.x,g.y), pk2(g.z,g.w), pk2(h.x,h.y),   pk2(h.z,h.w));
        }
        __syncthreads();
        #pragma unroll
        for (int h = 0; h < 2; ++h) {     // K frag gather from T2 (uint4 each)
            int ch = tid + h * 256;       // 0..511: [w][half][ln]
            int w = ch >> 7, half = (ch >> 6) & 1, ln = ch & 63;
            int row = w * 16 + (ln & 15), col = half * 32 + (ln >> 4) * 8;
            uint4 val = *(const uint4*)&T2[row * 80 + col];
            unsigned short* dst = KF + (size_t)pair * 131072 + kvt2 * 8192
                                + w * 2048 + parity * 1024 + half * 512 + ln * 8;
            *(uint4*)dst = val;
        }
        #pragma unroll
        for (int h = 0; h < 4; ++h) {     // V paired-frag halves from T (uint2 each)
            int idx = h * 256 + tid;      // 0..1023: [w][dt][lane]
            int w = idx >> 8, dt = (idx >> 6) & 3, ln = idx & 63;
            int quad = ln >> 4, l16 = ln & 15;
            int kvloc = w * 16 + quad * 4, d = dt * 16 + l16;
            unsigned int u0 = (unsigned int)T[(kvloc+0)*72+d] | ((unsigned int)T[(kvloc+1)*72+d] << 16);
            unsigned int u1 = (unsigned int)T[(kvloc+2)*72+d] | ((unsigned int)T[(kvloc+3)*72+d] << 16);
            unsigned short* dst = VF + (size_t)pair * 131072 + kvt2 * 8192
                                + w * 2048 + dt * 512 + ln * 8 + parity * 4;
            *(uint2*)dst = make_uint2(u0, u1);
        }
    } else {                              // W -> bf16 (b-1024 in 0..255)
        size_t base = (size_t)(b - 1024) * 4096 + tid * 16;
        const float* s = W + base;
        float4 a = *(const float4*)s,       bb = *(const float4*)(s + 4);
        float4 c = *(const float4*)(s + 8), d  = *(const float4*)(s + 12);
        *(uint4*)(Wb + base)     = make_uint4(pk2(a.x,a.y), pk2(a.z,a.w), pk2(bb.x,bb.y), pk2(bb.z,bb.w));
        *(uint4*)(Wb + base + 8) = make_uint4(pk2(c.x,c.y), pk2(c.z,c.w), pk2(d.x,d.y), pk2(d.z,d.w));
    }
}

// MFMA clusters + softmax macros — nt=2 (reverted from round-12's nt=4 regression)
#define DO_QK(K0_,K1_,K2_,K3_)                                                            \
    {                                                                                     \
        s8v ak00 = asv(K0_), ak01 = asv(K1_), ak10 = asv(K2_), ak11 = asv(K3_);           \
        __builtin_amdgcn_s_setprio(1);                                                    \
        _Pragma("unroll")                                                                 \
        for (int nt = 0; nt < 2; ++nt) {                                                  \
            f4v z = (f4v){0.f, 0.f, 0.f, 0.f};                                            \
            z      = __builtin_amdgcn_mfma_f32_16x16x32_bf16(ak00, bq[nt][0], z, 0, 0, 0);\
            s0[nt] = __builtin_amdgcn_mfma_f32_16x16x32_bf16(ak01, bq[nt][1], z, 0, 0, 0);\
            f4v w = (f4v){0.f, 0.f, 0.f, 0.f};                                            \
            w      = __builtin_amdgcn_mfma_f32_16x16x32_bf16(ak10, bq[nt][0], w, 0, 0, 0);\
            s1[nt] = __builtin_amdgcn_mfma_f32_16x16x32_bf16(ak11, bq[nt][1], w, 0, 0, 0);\
        }                                                                                 \
        __builtin_amdgcn_s_setprio(0);                                                    \
    }

#define DO_SM()                                                                           \
    _Pragma("unroll")                                                                     \
    for (int nt = 0; nt < 2; ++nt) {                                                      \
        float e0 = fexp2(s0[nt][0]), e1 = fexp2(s0[nt][1]);                               \
        float e2 = fexp2(s0[nt][2]), e3 = fexp2(s0[nt][3]);                               \
        float f0 = fexp2(s1[nt][0]), f1 = fexp2(s1[nt][1]);                               \
        float f2 = fexp2(s1[nt][2]), f3 = fexp2(s1[nt][3]);                               \
        psum[nt] += ((e0 + e1) + (e2 + e3)) + ((f0 + f1) + (f2 + f3));                    \
        U4 c; c.u = make_uint4(cvtpk(e0, e1), cvtpk(e2, e3), cvtpk(f0, f1), cvtpk(f2, f3));\
        bp[nt] = c.v;                                                                     \
    }

#define DO_PV(V0_,V1_,V2_,V3_)                                                            \
    {                                                                                     \
        s8v av0 = asv(V0_), av1 = asv(V1_), av2 = asv(V2_), av3 = asv(V3_);               \
        __builtin_amdgcn_s_setprio(1);                                                    \
        _Pragma("unroll")                                                                 \
        for (int nt = 0; nt < 2; ++nt) {                                                  \
            acc[0][nt] = __builtin_amdgcn_mfma_f32_16x16x32_bf16(av0, bp[nt], acc[0][nt], 0, 0, 0); \
            acc[1][nt] = __builtin_amdgcn_mfma_f32_16x16x32_bf16(av1, bp[nt], acc[1][nt], 0, 0, 0); \
            acc[2][nt] = __builtin_amdgcn_mfma_f32_16x16x32_bf16(av2, bp[nt], acc[2][nt], 0, 0, 0); \
            acc[3][nt] = __builtin_amdgcn_mfma_f32_16x16x32_bf16(av3, bp[nt], acc[3][nt], 0, 0, 0); \
        }                                                                                 \
        __builtin_amdgcn_s_setprio(0);                                                    \
    }

// ============ fused attention: 16-wave blocks (4 qq x 4 kv4), 32 waves/CU ============
// ROUND-13: r12 proved the kernel is TLP-starved (halving waves/CU cost +17%); the
// 16-waves/CU cap came from grid 512 x 8-wave blocks. Escape: split kv across waves
// WITHIN the block — 16 waves = 4 qq x 4 kv4, each wave owns ONE 16-row kv slice per
// tile-pair. Per-wave code/regs/LDS-reads and total staged bytes are IDENTICAL to
// round-10's proven 49.6-us structure; only the wave count doubles: grid 512 x 16
// waves = 32 waves/CU (hardware max). Loop = 16 iters (tile-pairs), all 8 slices
// (4 K + 4 V = 32 KB) staged per iter, 2-buffer = 64 KB LDS -> exactly 2 blocks/CU.
// (1024, 8) = 64-reg cap: r10 compiled this exact per-wave body to 52 regs, no spill.
// Epilogue: 4-phase kv4 reduce into Opool.
__global__ __launch_bounds__(1024, 8)
void attn_kernel(const float* __restrict__ Q, const unsigned short* __restrict__ KF,
                 const unsigned short* __restrict__ VF, unsigned short* __restrict__ X) {
    __shared__ __attribute__((aligned(16))) unsigned char SMEM[65536];   // 2 x 32 KB
    unsigned short (*SB)[8][2048] = (unsigned short (*)[8][2048])SMEM;   // [buf][region][idx]
    float* Opool = (float*)SMEM;            // epilogue alias: 64 x 130 f32 = 33.3 KB
    float* Psum  = Opool + 64 * 130;        // 512 f32

    const int bid  = blockIdx.x;
    const int pair = bid & 31;
    const int qt   = bid >> 5;              // 0..15, 128 q-rows each
    const int tid  = threadIdx.x;
    const int wave = tid >> 6, lane = tid & 63, quad = lane >> 4, l16 = lane & 15;
    const int kv4 = wave & 3, qq = wave >> 2;   // kv slice (0..3), q-subtile (0..3)

    // staging role: region r = wave>>1 (0..7): r<4 -> K slice r, r>=4 -> V slice r-4;
    // half h = wave&1 (1 KB x 2 within the 4 KB region). LDS dest wave-uniform.
    const int sreg = wave >> 1, sh = wave & 1;
    const unsigned short* SRC = (sreg < 4 ? KF : VF) + (size_t)pair * 131072
                              + (size_t)(sreg & 3) * 2048 + (size_t)sh * 1024
                              + (size_t)lane * 8;

    // hoist Q B-frags from global, PRE-SCALED by C1: B[n=q][k=d=kt*32+quad*8+j]
    s8v bq[2][2];
    #pragma unroll
    for (int nt = 0; nt < 2; ++nt)
        #pragma unroll
        for (int kt = 0; kt < 2; ++kt) {
            const float* src = Q + (size_t)(pair * SLEN + qt * 128 + qq * 32 + nt * 16 + l16) * 64 + kt * 32 + quad * 8;
            float4 f0 = *(const float4*)src;
            float4 f1 = *(const float4*)(src + 4);
            U4 c; c.u = make_uint4(pk2(f0.x * C1, f0.y * C1), pk2(f0.z * C1, f0.w * C1),
                                   pk2(f1.x * C1, f1.y * C1), pk2(f1.z * C1, f1.w * C1));
            bq[nt][kt] = c.v;
        }

    f4v acc[4][2];   // O^T tiles [dt][nt]: row = d-local quad*4+reg, col = q-local l16
    #pragma unroll
    for (int i = 0; i < 4; ++i)
        #pragma unroll
        for (int j = 0; j < 2; ++j) acc[i][j] = (f4v){0.f, 0.f, 0.f, 0.f};
    float psum[2] = {0.f, 0.f};

    // prologue: stage tile-pair 0 into buf 0
    #pragma unroll
    for (int j = 0; j < 2; ++j)
        __builtin_amdgcn_global_load_lds(
            (const __attribute__((address_space(1))) unsigned int*)(SRC + j * 512),
            (__attribute__((address_space(3))) unsigned int*)&SB[0][sreg][sh * 1024 + j * 512],
            16, 0, 0);
    __syncthreads();

    f4v s0[2], s1[2];
    s8v bp[2];

    for (int i = 0; i < 16; ++i) {   // i = tile-pair
        const int buf = i & 1;
        if (i < 15) {                // stage next tile-pair into the other buffer
            const unsigned short* s = SRC + (size_t)(i + 1) * 8192;
            #pragma unroll
            for (int j = 0; j < 2; ++j)
                __builtin_amdgcn_global_load_lds(
                    (const __attribute__((address_space(1))) unsigned int*)(s + j * 512),
                    (__attribute__((address_space(3))) unsigned int*)&SB[buf ^ 1][sreg][sh * 1024 + j * 512],
                    16, 0, 0);
        }

        const unsigned short* kreg = &SB[buf][kv4][(size_t)lane * 8];
        const unsigned short* vreg = &SB[buf][4 + kv4][(size_t)lane * 8];
        uint4 cK0 = *(const uint4*)kreg;            uint4 cK1 = *(const uint4*)(kreg + 512);
        uint4 cK2 = *(const uint4*)(kreg + 1024);   uint4 cK3 = *(const uint4*)(kreg + 1536);
        uint4 cV0 = *(const uint4*)vreg;            uint4 cV1 = *(const uint4*)(vreg + 512);
        uint4 cV2 = *(const uint4*)(vreg + 1024);   uint4 cV3 = *(const uint4*)(vreg + 1536);

        DO_QK(cK0, cK1, cK2, cK3);
        DO_SM();
        DO_PV(cV0, cV1, cV2, cV3);

        __syncthreads();   // drains my stage (vmcnt 0) + all waves done reading buf
    }

    // ---- epilogue: 4-way kv4 reduce of O^T and psum, normalize, store X (bf16) ----
    #pragma unroll
    for (int nt = 0; nt < 2; ++nt) {
        float p = psum[nt];
        p += __shfl_xor(p, 16);
        p += __shfl_xor(p, 32);
        psum[nt] = p;
    }
    if (quad == 0) {
        #pragma unroll
        for (int nt = 0; nt < 2; ++nt) Psum[kv4 * 128 + qq * 32 + nt * 16 + l16] = psum[nt];
    }
    // 4-phase Opool accumulate across kv4 groups (qq waves write disjoint columns)
    #pragma unroll
    for (int ph = 0; ph < 4; ++ph) {
        if (kv4 == ph) {
            #pragma unroll
            for (int dt = 0; dt < 4; ++dt)
                #pragma unroll
                for (int nt = 0; nt < 2; ++nt)
                    #pragma unroll
                    for (int reg = 0; reg < 4; ++reg) {
                        int idx = (dt * 16 + quad * 4 + reg) * 130 + qq * 32 + nt * 16 + l16;
                        if (ph == 0) Opool[idx] = acc[dt][nt][reg];
                        else         Opool[idx] += acc[dt][nt][reg];
                    }
        }
        __syncthreads();
    }
    {
        int q = tid & 127, d0 = (tid >> 7) * 8;   // 1024 threads: 128 q x 8 d-groups
        float inv = 1.0f / (((Psum[q] + Psum[128 + q]) + (Psum[256 + q] + Psum[384 + q])));
        float o[8];
        #pragma unroll
        for (int i = 0; i < 8; ++i) o[i] = Opool[(d0 + i) * 130 + q] * inv;
        unsigned short* xp = X + ((size_t)(pair * SLEN + qt * 128 + q)) * 64 + d0;
        *(uint4*)xp = make_uint4(pk2(o[0],o[1]), pk2(o[2],o[3]), pk2(o[4],o[5]), pk2(o[6],o[7]));
    }
}

// ============ out = x @ W^T + b (unchanged from round 8) ============
#define GSTR 40
__global__ __launch_bounds__(256)
void out_gemm(const unsigned short* __restrict__ X, const unsigned short* __restrict__ Wb,
              const float* __restrict__ bias, float* __restrict__ out) {
    __shared__ __attribute__((aligned(16))) unsigned short As[2][128 * GSTR];
    __shared__ __attribute__((aligned(16))) unsigned short Bs[2][128 * GSTR];
    const int bid = blockIdx.x;
    const int nblk = (bid >> 3) & 7;
    const int mblk = (bid & 7) | ((bid >> 6) << 3);
    const int tid = threadIdx.x;
    const int wave = tid >> 6, lane = tid & 63, quad = lane >> 4, l16 = lane & 15;
    const int wm = (wave & 1) * 64, wn = (wave >> 1) * 64;

    const unsigned short* Xp = X + (size_t)(mblk * 128 + (tid >> 1)) * 1024 + (tid & 1) * 16;
    const unsigned short* Wp = Wb + (size_t)(nblk * 128 + (tid >> 1)) * 1024 + (tid & 1) * 16;
    const int ar = (tid >> 1) * GSTR + (tid & 1) * 16;

    uint4 xa = *(const uint4*)Xp, xb = *(const uint4*)(Xp + 8);
    uint4 wa = *(const uint4*)Wp, wb = *(const uint4*)(Wp + 8);

    f4v acc[4][4];
    #pragma unroll
    for (int i = 0; i < 4; ++i)
        #pragma unroll
        for (int j = 0; j < 4; ++j) acc[i][j] = (f4v){0.f, 0.f, 0.f, 0.f};

    for (int it = 0; it < 32; ++it) {
        const int cur = it & 1;
        *(uint4*)&As[cur][ar]     = xa;
        *(uint4*)&As[cur][ar + 8] = xb;
        *(uint4*)&Bs[cur][ar]     = wa;
        *(uint4*)&Bs[cur][ar + 8] = wb;
        __syncthreads();
        if (it < 31) {
            Xp += 32; Wp += 32;
            xa = *(const uint4*)Xp; xb = *(const uint4*)(Xp + 8);
            wa = *(const uint4*)Wp; wb = *(const uint4*)(Wp + 8);
        }
        s8v af[4], bf[4];
        #pragma unroll
        for (int mt = 0; mt < 4; ++mt)
            af[mt] = *(const s8v*)&As[cur][(wm + mt * 16 + l16) * GSTR + quad * 8];
        #pragma unroll
        for (int nt = 0; nt < 4; ++nt)
            bf[nt] = *(const s8v*)&Bs[cur][(wn + nt * 16 + l16) * GSTR + quad * 8];
        #pragma unroll
        for (int mt = 0; mt < 4; ++mt)
            #pragma unroll
            for (int nt = 0; nt < 4; ++nt)
                acc[mt][nt] = __builtin_amdgcn_mfma_f32_16x16x32_bf16(af[mt], bf[nt], acc[mt][nt], 0, 0, 0);
    }

    #pragma unroll
    for (int nt = 0; nt < 4; ++nt) {
        int col = nblk * 128 + wn + nt * 16 + l16;
        float bv = bias[col];
        #pragma unroll
        for (int mt = 0; mt < 4; ++mt) {
            int row = mblk * 128 + wm + mt * 16 + quad * 4;
            float* o = out + (size_t)row * 1024 + col;
            o[0]    = acc[mt][nt][0] + bv;
            o[1024] = acc[mt][nt][1] + bv;
            o[2048] = acc[mt][nt][2] + bv;
            o[3072] = acc[mt][nt][3] + bv;
        }
    }
}

extern "C" void kernel_launch(void* const* d_in, const int* in_sizes, int n_in,
                              void* d_out, int out_size, void* d_ws, size_t ws_size,
                              hipStream_t stream) {
    const float* Q    = (const float*)d_in[0];
    const float* K    = (const float*)d_in[1];
    const float* V    = (const float*)d_in[2];
    const float* W    = (const float*)d_in[4];
    const float* bias = (const float*)d_in[5];
    float* out = (float*)d_out;

    unsigned short* ws = (unsigned short*)d_ws;   // ~28 MB of workspace used
    unsigned short* X  = ws;                      // 8 MB bf16 attention output
    unsigned short* KF = ws + 4194304;            // 8 MB K fragment tiles
    unsigned short* VF = ws + 8388608;            // 8 MB V paired-fragment tiles
    unsigned short* Wb = ws + 12582912;           // 2 MB bf16 W

    prep_kernel<<<1280, 256, 0, stream>>>(K, V, W, KF, VF, Wb);
    attn_kernel<<<512, 1024, 0, stream>>>(Q, KF, VF, X);
    out_gemm<<<256, 256, 0, stream>>>(X, Wb, bias, out);
}

// Round 14
// 167.362 us; speedup vs baseline: 2.8394x; 2.8394x over previous
//
#include <hip/hip_runtime.h>

typedef __attribute__((ext_vector_type(8))) short s8v;   // 8 x bf16 (4 VGPRs)
typedef __attribute__((ext_vector_type(4))) float f4v;   // mfma accumulator

#define LOG2E 1.44269504088896340736f
#define C1 (0.125f * LOG2E)
#define SLEN 2048

union U4 { uint4 u; s8v v; };
static __device__ __forceinline__ s8v asv(uint4 u) { U4 c; c.u = u; return c.v; }

// fp32 -> bf16 round-half-up pack: low short = bf16(a), high short = bf16(b)
static __device__ __forceinline__ unsigned int pk2(float a, float b) {
    unsigned int ua = __float_as_uint(a) + 0x8000u;
    unsigned int ub = __float_as_uint(b) + 0x8000u;
    return __builtin_amdgcn_perm(ub, ua, 0x07060302u);
}

// single-instr RNE pack (hot loop only): low = bf16(a), high = bf16(b)
static __device__ __forceinline__ unsigned int cvtpk(float a, float b) {
    unsigned int r;
    asm("v_cvt_pk_bf16_f32 %0, %1, %2" : "=v"(r) : "v"(a), "v"(b));
    return r;
}

// raw HW exp2: 1 TRANS instr (libm exp2f expands to ~7; FTZ is right for softmax)
static __device__ __forceinline__ float fexp2(float x) {
    float r;
    asm("v_exp_f32 %0, %1" : "=v"(r) : "v"(x));
    return r;
}

// ============ prep: one-shot bf16 conversion into PER-WAVE FRAGMENT order ============
__global__ __launch_bounds__(256)
void prep_kernel(const float* __restrict__ K, const float* __restrict__ V,
                 const float* __restrict__ W,
                 unsigned short* __restrict__ KF, unsigned short* __restrict__ VF,
                 unsigned short* __restrict__ Wb) {
    __shared__ __attribute__((aligned(16))) unsigned short T[64 * 72];    // V tile
    __shared__ __attribute__((aligned(16))) unsigned short T2[64 * 80];   // K tile
    const int b = blockIdx.x, tid = threadIdx.x;
    if (b < 1024) {                       // K + V tile job: b = pair*32 + kvt
        const int pair = b >> 5, kvt = b & 31, kvt2 = kvt >> 1, parity = kvt & 1;
        const float* Kf = K + (size_t)b * 4096;
        const float* Vf = V + (size_t)b * 4096;
        {   // stage V -> T[kv][72] and K -> T2[kv][80], both coalesced
            int r = tid >> 2, c0 = (tid & 3) * 16;
            const float* sv = Vf + r * 64 + c0;
            float4 a = *(const float4*)sv,       bb = *(const float4*)(sv + 4);
            float4 c = *(const float4*)(sv + 8), d  = *(const float4*)(sv + 12);
            *(uint4*)&T[r * 72 + c0]     = make_uint4(pk2(a.x,a.y), pk2(a.z,a.w), pk2(bb.x,bb.y), pk2(bb.z,bb.w));
            *(uint4*)&T[r * 72 + c0 + 8] = make_uint4(pk2(c.x,c.y), pk2(c.z,c.w), pk2(d.x,d.y),   pk2(d.z,d.w));
            const float* sk = Kf + r * 64 + c0;
            float4 e = *(const float4*)sk,       ff = *(const float4*)(sk + 4);
            float4 g = *(const float4*)(sk + 8), h  = *(const float4*)(sk + 12);
            *(uint4*)&T2[r * 80 + c0]     = make_uint4(pk2(e.x,e.y), pk2(e.z,e.w), pk2(ff.x,ff.y), pk2(ff.z,ff.w));
            *(uint4*)&T2[r * 80 + c0 + 8] = make_uint4(pk2(g.x,g.y), pk2(g.z,g.w), pk2(h.x,h.y),   pk2(h.z,h.w));
        }
        __syncthreads();
        #pragma unroll
        for (int h = 0; h < 2; ++h) {     // K frag gather from T2 (uint4 each)
            int ch = tid + h * 256;       // 0..511: [w][half][ln]
            int w = ch >> 7, half = (ch >> 6) & 1, ln = ch & 63;
            int row = w * 16 + (ln & 15), col = half * 32 + (ln >> 4) * 8;
            uint4 val = *(const uint4*)&T2[row * 80 + col];
            unsigned short* dst = KF + (size_t)pair * 131072 + kvt2 * 8192
                                + w * 2048 + parity * 1024 + half * 512 + ln * 8;
            *(uint4*)dst = val;
        }
        #pragma unroll
        for (int h = 0; h < 4; ++h) {     // V paired-frag halves from T (uint2 each)
            int idx = h * 256 + tid;      // 0..1023: [w][dt][lane]
            int w = idx >> 8, dt = (idx >> 6) & 3, ln = idx & 63;
            int quad = ln >> 4, l16 = ln & 15;
            int kvloc = w * 16 + quad * 4, d = dt * 16 + l16;
            unsigned int u0 = (unsigned int)T[(kvloc+0)*72+d] | ((unsigned int)T[(kvloc+1)*72+d] << 16);
            unsigned int u1 = (unsigned int)T[(kvloc+2)*72+d] | ((unsigned int)T[(kvloc+3)*72+d] << 16);
            unsigned short* dst = VF + (size_t)pair * 131072 + kvt2 * 8192
                                + w * 2048 + dt * 512 + ln * 8 + parity * 4;
            *(uint2*)dst = make_uint2(u0, u1);
        }
    } else {                              // W -> bf16 (b-1024 in 0..255)
        size_t base = (size_t)(b - 1024) * 4096 + tid * 16;
        const float* s = W + base;
        float4 a = *(const float4*)s,       bb = *(const float4*)(s + 4);
        float4 c = *(const float4*)(s + 8), d  = *(const float4*)(s + 12);
        *(uint4*)(Wb + base)     = make_uint4(pk2(a.x,a.y), pk2(a.z,a.w), pk2(bb.x,bb.y), pk2(bb.z,bb.w));
        *(uint4*)(Wb + base + 8) = make_uint4(pk2(c.x,c.y), pk2(c.z,c.w), pk2(d.x,d.y), pk2(d.z,d.w));
    }
}

// MFMA clusters + softmax macros (nt=2, round-10 proven)
#define DO_QK(K0_,K1_,K2_,K3_)                                                            \
    {                                                                                     \
        s8v ak00 = asv(K0_), ak01 = asv(K1_), ak10 = asv(K2_), ak11 = asv(K3_);           \
        __builtin_amdgcn_s_setprio(1);                                                    \
        _Pragma("unroll")                                                                 \
        for (int nt = 0; nt < 2; ++nt) {                                                  \
            f4v z = (f4v){0.f, 0.f, 0.f, 0.f};                                            \
            z      = __builtin_amdgcn_mfma_f32_16x16x32_bf16(ak00, bq[nt][0], z, 0, 0, 0);\
            s0[nt] = __builtin_amdgcn_mfma_f32_16x16x32_bf16(ak01, bq[nt][1], z, 0, 0, 0);\
            f4v w = (f4v){0.f, 0.f, 0.f, 0.f};                                            \
            w      = __builtin_amdgcn_mfma_f32_16x16x32_bf16(ak10, bq[nt][0], w, 0, 0, 0);\
            s1[nt] = __builtin_amdgcn_mfma_f32_16x16x32_bf16(ak11, bq[nt][1], w, 0, 0, 0);\
        }                                                                                 \
        __builtin_amdgcn_s_setprio(0);                                                    \
    }

#define DO_SM()                                                                           \
    _Pragma("unroll")                                                                     \
    for (int nt = 0; nt < 2; ++nt) {                                                      \
        float e0 = fexp2(s0[nt][0]), e1 = fexp2(s0[nt][1]);                               \
        float e2 = fexp2(s0[nt][2]), e3 = fexp2(s0[nt][3]);                               \
        float f0 = fexp2(s1[nt][0]), f1 = fexp2(s1[nt][1]);                               \
        float f2 = fexp2(s1[nt][2]), f3 = fexp2(s1[nt][3]);                               \
        psum[nt] += ((e0 + e1) + (e2 + e3)) + ((f0 + f1) + (f2 + f3));                    \
        U4 c; c.u = make_uint4(cvtpk(e0, e1), cvtpk(e2, e3), cvtpk(f0, f1), cvtpk(f2, f3));\
        bp[nt] = c.v;                                                                     \
    }

#define DO_PV(V0_,V1_,V2_,V3_)                                                            \
    {                                                                                     \
        s8v av0 = asv(V0_), av1 = asv(V1_), av2 = asv(V2_), av3 = asv(V3_);               \
        __builtin_amdgcn_s_setprio(1);                                                    \
        _Pragma("unroll")                                                                 \
        for (int nt = 0; nt < 2; ++nt) {                                                  \
            acc[0][nt] = __builtin_amdgcn_mfma_f32_16x16x32_bf16(av0, bp[nt], acc[0][nt], 0, 0, 0); \
            acc[1][nt] = __builtin_amdgcn_mfma_f32_16x16x32_bf16(av1, bp[nt], acc[1][nt], 0, 0, 0); \
            acc[2][nt] = __builtin_amdgcn_mfma_f32_16x16x32_bf16(av2, bp[nt], acc[2][nt], 0, 0, 0); \
            acc[3][nt] = __builtin_amdgcn_mfma_f32_16x16x32_bf16(av3, bp[nt], acc[3][nt], 0, 0, 0); \
        }                                                                                 \
        __builtin_amdgcn_s_setprio(0);                                                    \
    }

// ============ fused attention: 8-wave blocks, 128 q-rows, shared LDS staging ============
// ROUND-14: REVERT to the round-10 configuration — the session's best measured state
// (attn 49.6 us, total 163.9 us). Post-r13 audit: per-wave state = ~52 VGPR + ~48 AGPR
// ~= 100 regs against the unified cap, so 32 waves/CU (64-reg cap) is structurally
// impossible for this fragment scheme (r13: spill, 965 MB scratch, 356 us). The tested
// alternatives all regressed or were null: counted-vmcnt (r11 null), nt=4 register
// blocking (r12 -17%, TLP loss), max-TLP (r13 spill). 16 waves/CU at 2 blocks/CU with
// barrier-per-half-iter is this scheme's operating point.
__global__ __launch_bounds__(512, 4)
void attn_kernel(const float* __restrict__ Q, const unsigned short* __restrict__ KF,
                 const unsigned short* __restrict__ VF, unsigned short* __restrict__ X) {
    __shared__ __attribute__((aligned(16))) unsigned char SMEM[34816];
    unsigned short (*SB)[4][2048] = (unsigned short (*)[4][2048])SMEM;  // [buf][region][idx]
    float* Opool = (float*)SMEM;            // epilogue alias (64*130*4 + 1KB = 34.3 KB)
    float* Psum  = Opool + 64 * 130;

    const int bid  = blockIdx.x;
    const int pair = bid & 31;
    const int qt   = bid >> 5;              // 0..15, 128 q-rows each
    const int tid  = threadIdx.x;
    const int wave = tid >> 6, lane = tid & 63, quad = lane >> 4, l16 = lane & 15;
    const int kvh = wave & 1, qq = wave >> 1;   // kv-half, q-subtile (0..3)

    // staging role: region r = wave>>1 (0=K slc+0, 1=K slc+2, 2=V slc+0, 3=V slc+2),
    // half h = wave&1 (1 KB x 2 within the region). src per-lane; LDS dest wave-uniform.
    const int sreg = wave >> 1, sh = wave & 1;
    const unsigned short* SRC = (sreg < 2 ? KF : VF) + (size_t)pair * 131072
                              + (size_t)lane * 8;
    const int sliceAdd = (sreg & 1) * 2;

    // hoist Q B-frags from global, PRE-SCALED by C1: B[n=q][k=d=kt*32+quad*8+j]
    s8v bq[2][2];
    #pragma unroll
    for (int nt = 0; nt < 2; ++nt)
        #pragma unroll
        for (int kt = 0; kt < 2; ++kt) {
            const float* src = Q + (size_t)(pair * SLEN + qt * 128 + qq * 32 + nt * 16 + l16) * 64 + kt * 32 + quad * 8;
            float4 f0 = *(const float4*)src;
            float4 f1 = *(const float4*)(src + 4);
            U4 c; c.u = make_uint4(pk2(f0.x * C1, f0.y * C1), pk2(f0.z * C1, f0.w * C1),
                                   pk2(f1.x * C1, f1.y * C1), pk2(f1.z * C1, f1.w * C1));
            bq[nt][kt] = c.v;
        }

    f4v acc[4][2];   // O^T tiles [dt][nt]: row = d-local quad*4+reg, col = q-local l16
    #pragma unroll
    for (int i = 0; i < 4; ++i)
        #pragma unroll
        for (int j = 0; j < 2; ++j) acc[i][j] = (f4v){0.f, 0.f, 0.f, 0.f};
    float psum[2] = {0.f, 0.f};

    // prologue: stage half-iter 0 into buf 0 (sub=0, tile-pair 0)
    {
        const unsigned short* s = SRC + (size_t)sliceAdd * 2048 + (size_t)sh * 1024;
        #pragma unroll
        for (int j = 0; j < 2; ++j)
            __builtin_amdgcn_global_load_lds(
                (const __attribute__((address_space(1))) unsigned int*)(s + j * 512),
                (__attribute__((address_space(3))) unsigned int*)&SB[0][sreg][sh * 1024 + j * 512],
                16, 0, 0);
    }
    __syncthreads();

    f4v s0[2], s1[2];
    s8v bp[2];

    for (int i = 0; i < 32; ++i) {   // half-iter: sub = i>>4, tile-pair = i&15
        const int buf = i & 1;
        const int nx = (i < 31) ? i + 1 : 31;   // last iter restages itself (unused)
        const unsigned short* s = SRC + ((size_t)(nx & 15) * 8192
                              + (size_t)((nx >> 4) + sliceAdd) * 2048 + (size_t)sh * 1024);
        #pragma unroll
        for (int j = 0; j < 2; ++j)
            __builtin_amdgcn_global_load_lds(
                (const __attribute__((address_space(1))) unsigned int*)(s + j * 512),
                (__attribute__((address_space(3))) unsigned int*)&SB[buf ^ 1][sreg][sh * 1024 + j * 512],
                16, 0, 0);

        const unsigned short* kreg = &SB[buf][kvh][(size_t)lane * 8];
        const unsigned short* vreg = &SB[buf][2 + kvh][(size_t)lane * 8];
        uint4 cK0 = *(const uint4*)kreg;            uint4 cK1 = *(const uint4*)(kreg + 512);
        uint4 cK2 = *(const uint4*)(kreg + 1024);   uint4 cK3 = *(const uint4*)(kreg + 1536);
        uint4 cV0 = *(const uint4*)vreg;            uint4 cV1 = *(const uint4*)(vreg + 512);
        uint4 cV2 = *(const uint4*)(vreg + 1024);   uint4 cV3 = *(const uint4*)(vreg + 1536);

        DO_QK(cK0, cK1, cK2, cK3);
        DO_SM();
        DO_PV(cV0, cV1, cV2, cV3);

        __syncthreads();   // drains my stage (vmcnt 0) + all waves done reading buf
    }

    // ---- epilogue: 2-way kv reduce of O^T and psum, normalize, store X (bf16) ----
    #pragma unroll
    for (int nt = 0; nt < 2; ++nt) {
        float p = psum[nt];
        p += __shfl_xor(p, 16);
        p += __shfl_xor(p, 32);
        psum[nt] = p;
    }
    if (quad == 0) {
        #pragma unroll
        for (int nt = 0; nt < 2; ++nt) Psum[kvh * 128 + qq * 32 + nt * 16 + l16] = psum[nt];
    }
    if (kvh == 0) {   // 4 qq-waves write disjoint column ranges
        #pragma unroll
        for (int dt = 0; dt < 4; ++dt)
            #pragma unroll
            for (int nt = 0; nt < 2; ++nt)
                #pragma unroll
                for (int reg = 0; reg < 4; ++reg)
                    Opool[(dt * 16 + quad * 4 + reg) * 130 + qq * 32 + nt * 16 + l16] = acc[dt][nt][reg];
    }
    __syncthreads();
    if (kvh == 1) {   // other kv-half accumulates
        #pragma unroll
        for (int dt = 0; dt < 4; ++dt)
            #pragma unroll
            for (int nt = 0; nt < 2; ++nt)
                #pragma unroll
                for (int reg = 0; reg < 4; ++reg)
                    Opool[(dt * 16 + quad * 4 + reg) * 130 + qq * 32 + nt * 16 + l16] += acc[dt][nt][reg];
    }
    __syncthreads();
    {
        int q = tid & 127, d0 = (tid >> 7) * 16;
        float inv = 1.0f / (Psum[q] + Psum[128 + q]);
        float o[16];
        #pragma unroll
        for (int i = 0; i < 16; ++i) o[i] = Opool[(d0 + i) * 130 + q] * inv;
        unsigned short* xp = X + ((size_t)(pair * SLEN + qt * 128 + q)) * 64 + d0;
        *(uint4*)xp       = make_uint4(pk2(o[0],o[1]),  pk2(o[2],o[3]),   pk2(o[4],o[5]),   pk2(o[6],o[7]));
        *(uint4*)(xp + 8) = make_uint4(pk2(o[8],o[9]),  pk2(o[10],o[11]), pk2(o[12],o[13]), pk2(o[14],o[15]));
    }
}

// ============ out = x @ W^T + b (round-8/10 config) ============
#define GSTR 40
__global__ __launch_bounds__(256)
void out_gemm(const unsigned short* __restrict__ X, const unsigned short* __restrict__ Wb,
              const float* __restrict__ bias, float* __restrict__ out) {
    __shared__ __attribute__((aligned(16))) unsigned short As[2][128 * GSTR];
    __shared__ __attribute__((aligned(16))) unsigned short Bs[2][128 * GSTR];
    const int bid = blockIdx.x;
    const int nblk = (bid >> 3) & 7;
    const int mblk = (bid & 7) | ((bid >> 6) << 3);
    const int tid = threadIdx.x;
    const int wave = tid >> 6, lane = tid & 63, quad = lane >> 4, l16 = lane & 15;
    const int wm = (wave & 1) * 64, wn = (wave >> 1) * 64;

    const unsigned short* Xp = X + (size_t)(mblk * 128 + (tid >> 1)) * 1024 + (tid & 1) * 16;
    const unsigned short* Wp = Wb + (size_t)(nblk * 128 + (tid >> 1)) * 1024 + (tid & 1) * 16;
    const int ar = (tid >> 1) * GSTR + (tid & 1) * 16;

    uint4 xa = *(const uint4*)Xp, xb = *(const uint4*)(Xp + 8);
    uint4 wa = *(const uint4*)Wp, wb = *(const uint4*)(Wp + 8);

    f4v acc[4][4];
    #pragma unroll
    for (int i = 0; i < 4; ++i)
        #pragma unroll
        for (int j = 0; j < 4; ++j) acc[i][j] = (f4v){0.f, 0.f, 0.f, 0.f};

    for (int it = 0; it < 32; ++it) {
        const int cur = it & 1;
        *(uint4*)&As[cur][ar]     = xa;
        *(uint4*)&As[cur][ar + 8] = xb;
        *(uint4*)&Bs[cur][ar]     = wa;
        *(uint4*)&Bs[cur][ar + 8] = wb;
        __syncthreads();
        if (it < 31) {
            Xp += 32; Wp += 32;
            xa = *(const uint4*)Xp; xb = *(const uint4*)(Xp + 8);
            wa = *(const uint4*)Wp; wb = *(const uint4*)(Wp + 8);
        }
        s8v af[4], bf[4];
        #pragma unroll
        for (int mt = 0; mt < 4; ++mt)
            af[mt] = *(const s8v*)&As[cur][(wm + mt * 16 + l16) * GSTR + quad * 8];
        #pragma unroll
        for (int nt = 0; nt < 4; ++nt)
            bf[nt] = *(const s8v*)&Bs[cur][(wn + nt * 16 + l16) * GSTR + quad * 8];
        #pragma unroll
        for (int mt = 0; mt < 4; ++mt)
            #pragma unroll
            for (int nt = 0; nt < 4; ++nt)
                acc[mt][nt] = __builtin_amdgcn_mfma_f32_16x16x32_bf16(af[mt], bf[nt], acc[mt][nt], 0, 0, 0);
    }

    #pragma unroll
    for (int nt = 0; nt < 4; ++nt) {
        int col = nblk * 128 + wn + nt * 16 + l16;
        float bv = bias[col];
        #pragma unroll
        for (int mt = 0; mt < 4; ++mt) {
            int row = mblk * 128 + wm + mt * 16 + quad * 4;
            float* o = out + (size_t)row * 1024 + col;
            o[0]    = acc[mt][nt][0] + bv;
            o[1024] = acc[mt][nt][1] + bv;
            o[2048] = acc[mt][nt][2] + bv;
            o[3072] = acc[mt][nt][3] + bv;
        }
    }
}

extern "C" void kernel_launch(void* const* d_in, const int* in_sizes, int n_in,
                              void* d_out, int out_size, void* d_ws, size_t ws_size,
                              hipStream_t stream) {
    const float* Q    = (const float*)d_in[0];
    const float* K    = (const float*)d_in[1];
    const float* V    = (const float*)d_in[2];
    const float* W    = (const float*)d_in[4];
    const float* bias = (const float*)d_in[5];
    float* out = (float*)d_out;

    unsigned short* ws = (unsigned short*)d_ws;   // ~28 MB of workspace used
    unsigned short* X  = ws;                      // 8 MB bf16 attention output
    unsigned short* KF = ws + 4194304;            // 8 MB K fragment tiles
    unsigned short* VF = ws + 8388608;            // 8 MB V paired-fragment tiles
    unsigned short* Wb = ws + 12582912;           // 2 MB bf16 W

    prep_kernel<<<1280, 256, 0, stream>>>(K, V, W, KF, VF, Wb);
    attn_kernel<<<512, 512, 0, stream>>>(Q, KF, VF, X);
    out_gemm<<<256, 256, 0, stream>>>(X, Wb, bias, out);
}